// Round 7
// baseline (450.314 us; speedup 1.0000x reference)
//
#include <hip/hip_runtime.h>

// ---------------------------------------------------------------------------
// SpatialTransformerPyramid2d, round 7: two-stage.
// N=64, c=32, H=W=128, outdims=4096, SCALE_N=4.
//
// r6 post-mortem: 256-thr and 512-thr configs gave IDENTICAL time and
// occupancy (42%) -> resident waves are throughput-limited (Little's law),
// not slot-limited.  Root cause: W table (1.44 MB) re-read by all 2048
// blocks = 2.95 GB L2 traffic + 8.4M atomics.  Fix requires c-loop INSIDE
// the out-parallel kernel:
//   Stage A: build each (n,c) pyramid in LDS (proven code), dump to ws
//            (2048 x 22.7 KB = 46.5 MB, L3-resident).
//   Stage B: block = (n, 64-out tile); W tile staged to LDS ONCE; threads
//            own outs, loop channels (4 waves x 8 c), taps read from the
//            global pyramid (tiny hot regions -> L1/L2), direct y store.
//   W traffic 2.95 GB -> 92 MB; atomics -> 0; init kernel gone.
//
// VGPR rule (measured r1-r6): __launch_bounds__(256,3) -> cap 84, no spill;
// never request more waves (forces 40 regs + GB-scale spills).
// ---------------------------------------------------------------------------

#define P1 66
#define P2 34
#define P3 18
#define P4 10
#define OFF_LO1 0                      // 64*66 = 4224
#define OFF_LO2 4224                   // 32*34 = 1088
#define OFF_LO3 5312                   // 16*18 = 288
#define OFF_LO4 5600                   // 8*10  = 80
#define SLOT    5680                   // floats per pyramid slot (22720 B)

#define G_A 0.0613609f
#define G_B 0.2447700f
#define G_C 0.3877386f

#define W4COUNT (22 * 4096)                     // float4s in W table
#define PYR_OFF_FLOATS (W4COUNT * 4)            // 360448 floats
#define WS_NEED ((size_t)PYR_OFF_FLOATS * 4 + (size_t)2048 * SLOT * 4)

static __device__ __forceinline__ float clampf(float v, float lo, float hi) {
    return fminf(fmaxf(v, lo), hi);
}
static __device__ __forceinline__ int imin(int a, int b) { return a < b ? a : b; }
static __device__ __forceinline__ int imax(int a, int b) { return a > b ? a : b; }

__global__ void init_out_kernel(const float* __restrict__ bias, float* __restrict__ y) {
    int i = blockIdx.x * blockDim.x + threadIdx.x;
    y[i] = bias[i & 4095];
}

// ---------------------------------------------------------------------------
// SoA weight table: float4 component m for point `out` at ws4[m*4096 + out].
//  m=0 : level-0 bilinear weights; m=1 : level-0 tap offsets (int bits)
//  m=2+5(j-1)+{0..4} : AX[4], BX[4], AY[3]+pad, BY[3]+pad, rowoffs[3]+pad
// ---------------------------------------------------------------------------
__global__ void weights_kernel(const float* __restrict__ grid, float* __restrict__ ws) {
    int out = blockIdx.x * blockDim.x + threadIdx.x;
    if (out >= 4096) return;
    float xs = clampf(grid[2 * out + 0], -1.f, 1.f);
    float ys = clampf(grid[2 * out + 1], -1.f, 1.f);
    float rec[88];

    float fx = (xs + 1.f) * 64.f - 0.5f;
    float fy = (ys + 1.f) * 64.f - 0.5f;
    float x0f = floorf(fx), y0f = floorf(fy);
    int x0 = (int)x0f, y0 = (int)y0f;
    float wx = fx - x0f, wy = fy - y0f;
    float ux0 = (x0 >= 0)      ? (1.f - wx) : 0.f;
    float ux1 = (x0 + 1 < 128) ? wx         : 0.f;
    float uy0 = (y0 >= 0)      ? (1.f - wy) : 0.f;
    float uy1 = (y0 + 1 < 128) ? wy         : 0.f;
    int cx0 = imax(x0, 0), cx1 = imin(x0 + 1, 127);
    int cy0 = imax(y0, 0), cy1 = imin(y0 + 1, 127);
    rec[0] = ux0 * uy0; rec[1] = ux1 * uy0; rec[2] = ux0 * uy1; rec[3] = ux1 * uy1;
    rec[4] = __int_as_float(cy0 * 128 + cx0);
    rec[5] = __int_as_float(cy0 * 128 + cx1);
    rec[6] = __int_as_float(cy1 * 128 + cx0);
    rec[7] = __int_as_float(cy1 * 128 + cx1);

    int   x0p = x0, y0p = y0;
    float ux0p = ux0, ux1p = ux1, uy0p = uy0, uy1p = uy1;

    const int offs[4]    = {OFF_LO1, OFF_LO2, OFF_LO3, OFF_LO4};
    const int strides[4] = {P1, P2, P3, P4};

    for (int j = 1; j <= 4; ++j) {
        const int Wj = 128 >> j, Pj = strides[j - 1], off = offs[j - 1];

        int qx; float a0, a1, a2;
        if (x0p & 1) { qx = (x0p - 1) >> 1;
            a0 = G_B * ux0p + G_A * ux1p; a1 = G_B * ux0p + G_C * ux1p; a2 = G_A * ux1p; }
        else         { qx = (x0p >> 1) - 1;
            a0 = G_A * ux0p; a1 = G_C * ux0p + G_B * ux1p; a2 = G_A * ux0p + G_B * ux1p; }
        int qy; float e0, e1, e2;
        if (y0p & 1) { qy = (y0p - 1) >> 1;
            e0 = G_B * uy0p + G_A * uy1p; e1 = G_B * uy0p + G_C * uy1p; e2 = G_A * uy1p; }
        else         { qy = (y0p >> 1) - 1;
            e0 = G_A * uy0p; e1 = G_C * uy0p + G_B * uy1p; e2 = G_A * uy0p + G_B * uy1p; }

        float half = (float)(Wj >> 1);
        float fxj = (xs + 1.f) * half - 0.5f;
        float fyj = (ys + 1.f) * half - 0.5f;
        float x0jf = floorf(fxj), y0jf = floorf(fyj);
        int x0j = (int)x0jf, y0j = (int)y0jf;
        float wxj = fxj - x0jf, wyj = fyj - y0jf;
        float ux0j = (x0j >= 0)     ? (1.f - wxj) : 0.f;
        float ux1j = (x0j + 1 < Wj) ? wxj         : 0.f;
        float uy0j = (y0j >= 0)     ? (1.f - wyj) : 0.f;
        float uy1j = (y0j + 1 < Wj) ? wyj         : 0.f;

        int bxb = qx & ~1;
        bxb = imin(imax(bxb, 0), Wj - 4);

        float* L = rec + 8 + (j - 1) * 20;
#pragma unroll
        for (int t = 0; t < 4; ++t) {
            int col = bxb + t;
            int s = col - qx;
            float av = (s == 0) ? a0 : (s == 1) ? a1 : (s == 2) ? a2 : 0.f;
            if (s < 0 || s > 2) av = 0.f;
            int sb = col - x0j;
            float bv = (sb == 0) ? ux0j : (sb == 1) ? ux1j : 0.f;
            L[t] = av;
            L[4 + t] = bv;
        }
#pragma unroll
        for (int t = 0; t < 3; ++t) {
            int row = qy + t;
            bool v = (row >= 0) && (row < Wj);
            float av = (t == 0) ? e0 : (t == 1) ? e1 : e2;
            L[8 + t] = v ? av : 0.f;
            int sb = row - y0j;
            L[12 + t] = (sb == 0) ? uy0j : (sb == 1) ? uy1j : 0.f;
            int rc = imin(imax(row, 0), Wj - 1);
            L[16 + t] = __int_as_float(off + rc * Pj + bxb);
        }
        L[11] = 0.f; L[15] = 0.f; L[19] = 0.f;

        x0p = x0j; y0p = y0j;
        ux0p = ux0j; ux1p = ux1j; uy0p = uy0j; uy1p = uy1j;
    }

    float4* W = (float4*)ws;
#pragma unroll
    for (int m = 0; m < 22; ++m)
        W[m * 4096 + out] = make_float4(rec[4 * m], rec[4 * m + 1],
                                        rec[4 * m + 2], rec[4 * m + 3]);
}

// smooth+downsample one point from LDS src (stride, logical S x S, zero pad)
static __device__ __forceinline__ float down_pt_lds(const float* s, int stride, int S,
                                                    int i, int j) {
    const float g1[5] = {G_A, G_B, G_C, G_B, G_A};
    int by = 2 * i - 2, bx = 2 * j - 2;
    float acc = 0.f;
    if (by >= 0 && by + 4 < S && bx >= 0 && bx + 4 < S) {
#pragma unroll
        for (int dy = 0; dy < 5; ++dy) {
            const float* r = s + (by + dy) * stride + bx;
            acc += g1[dy] * (G_A * (r[0] + r[4]) + G_B * (r[1] + r[3]) + G_C * r[2]);
        }
    } else {
#pragma unroll
        for (int dy = 0; dy < 5; ++dy) {
            int yy = by + dy;
            if ((unsigned)yy < (unsigned)S) {
#pragma unroll
                for (int dx = 0; dx < 5; ++dx) {
                    int xx = bx + dx;
                    if ((unsigned)xx < (unsigned)S)
                        acc += g1[dy] * g1[dx] * s[yy * stride + xx];
                }
            }
        }
    }
    return acc;
}

// build the 4-level lo pyramid for one 128x128 image into s_lo (ends synced)
static __device__ void build_pyramid(const float* __restrict__ img, float* s_lo, int tid) {
    const float g1[5] = {G_A, G_B, G_C, G_B, G_A};

    for (int r = tid; r < 1024; r += 256) {
        int i = r >> 4, j0 = (r & 15) << 2;
        int by = 2 * i - 2, bx = 2 * j0 - 2;
        float acc[4] = {0.f, 0.f, 0.f, 0.f};
        if (i >= 1 && i <= 62 && j0 >= 4 && j0 <= 56) {
#pragma unroll
            for (int dy = 0; dy < 5; ++dy) {
                const float* row = img + (by + dy) * 128 + bx;
                float v[11];
#pragma unroll
                for (int t = 0; t < 11; ++t) v[t] = row[t];
                float g = g1[dy];
#pragma unroll
                for (int jj = 0; jj < 4; ++jj) {
                    float h = G_A * (v[2 * jj] + v[2 * jj + 4]) +
                              G_B * (v[2 * jj + 1] + v[2 * jj + 3]) +
                              G_C * v[2 * jj + 2];
                    acc[jj] += g * h;
                }
            }
        } else {
#pragma unroll
            for (int dy = 0; dy < 5; ++dy) {
                int yy = by + dy;
                if ((unsigned)yy < 128u) {
#pragma unroll
                    for (int t = 0; t < 11; ++t) {
                        int xx = bx + t;
                        if ((unsigned)xx < 128u) {
                            float v = img[yy * 128 + xx];
#pragma unroll
                            for (int jj = 0; jj < 4; ++jj) {
                                int dx = t - 2 * jj;
                                if (dx >= 0 && dx <= 4) acc[jj] += g1[dy] * g1[dx] * v;
                            }
                        }
                    }
                }
            }
        }
        int base = OFF_LO1 + i * P1 + j0;
        *(float2*)&s_lo[base]     = make_float2(acc[0], acc[1]);
        *(float2*)&s_lo[base + 2] = make_float2(acc[2], acc[3]);
    }
    __syncthreads();

    for (int p = tid; p < 1024; p += 256) {
        int i = p >> 5, j = p & 31;
        s_lo[OFF_LO2 + i * P2 + j] = down_pt_lds(s_lo + OFF_LO1, P1, 64, i, j);
    }
    __syncthreads();

    {
        int i = tid >> 4, j = tid & 15;
        s_lo[OFF_LO3 + i * P3 + j] = down_pt_lds(s_lo + OFF_LO2, P2, 32, i, j);
    }
    __syncthreads();

    if (tid < 64) {
        int i = tid >> 3, j = tid & 7;
        s_lo[OFF_LO4 + i * P4 + j] = down_pt_lds(s_lo + OFF_LO3, P3, 16, i, j);
    }
    __syncthreads();
}

// ---- stage A: build all 2048 pyramids into global ws ----------------------
__global__ __launch_bounds__(256, 3) void pyr_build_kernel(
    const float* __restrict__ x, float* __restrict__ pyr)
{
    __shared__ __align__(16) float s_lo[SLOT];
    const int tid = threadIdx.x;
    const float* img = x + ((size_t)blockIdx.x << 14);
    build_pyramid(img, s_lo, tid);
    float4* dst = (float4*)(pyr + (size_t)blockIdx.x * SLOT);
    const float4* src = (const float4*)s_lo;
    for (int i = tid; i < SLOT / 4; i += 256) dst[i] = src[i];
}

// ---- stage B: block = (n, 64-out tile); c-loop inside ---------------------
__global__ __launch_bounds__(256, 3) void sample_kernel(
    const float* __restrict__ x, const float* __restrict__ wrec,
    const float* __restrict__ pyr, const float* __restrict__ feat,
    const float* __restrict__ bias, float* __restrict__ y)
{
    __shared__ __align__(16) float4 Wl[22 * 64];
    __shared__ float red[4][64];
    const int tid = threadIdx.x;
    const int n   = blockIdx.x >> 6;
    const int o0  = (blockIdx.x & 63) << 6;

    const float4* Wg = (const float4*)wrec;
    for (int i = tid; i < 22 * 64; i += 256)
        Wl[i] = Wg[(i >> 6) * 4096 + o0 + (i & 63)];
    __syncthreads();

    const int lane = tid & 63, q = tid >> 6;
    const int out  = o0 + lane;
    const float* xn = x + ((size_t)n << 19);            // n*32*16384
    const float* pn = pyr + (size_t)(n << 5) * SLOT;    // n*32 slots

    float4 w0 = Wl[lane];
    float4 t1 = Wl[64 + lane];
    int o00 = __float_as_int(t1.x), o01 = __float_as_int(t1.y);
    int o10 = __float_as_int(t1.z), o11 = __float_as_int(t1.w);

    float acc = 0.f;
    float fprev[8];
#pragma unroll 4
    for (int i = 0; i < 8; ++i) {
        const int c = q * 8 + i;
        const float* img = xn + ((size_t)c << 14);
        float f = feat[((size_t)c << 12) + out];
        float v0 = w0.x * img[o00] + w0.y * img[o01] +
                   w0.z * img[o10] + w0.w * img[o11];
        acc += f * v0;
        fprev[i] = f;
    }

#pragma unroll
    for (int j = 1; j <= 4; ++j) {
        const int mb = (2 + 5 * (j - 1)) * 64 + lane;
        float4 axw = Wl[mb];
        float4 bxw = Wl[mb + 64];
        float4 ayw = Wl[mb + 128];
        float4 byw = Wl[mb + 192];
        float4 rrf = Wl[mb + 256];
        int r0 = __float_as_int(rrf.x);
        int r1 = __float_as_int(rrf.y);
        int r2 = __float_as_int(rrf.z);

#pragma unroll 4
        for (int i = 0; i < 8; ++i) {
            const int c = q * 8 + i;
            const float* P = pn + (size_t)c * SLOT;
            float2 p0a = *(const float2*)(P + r0);
            float2 p0b = *(const float2*)(P + r0 + 2);
            float2 p1a = *(const float2*)(P + r1);
            float2 p1b = *(const float2*)(P + r1 + 2);
            float2 p2a = *(const float2*)(P + r2);
            float2 p2b = *(const float2*)(P + r2 + 2);
            float f = feat[((size_t)(j * 32 + c) << 12) + out];
            float ra0 = axw.x * p0a.x + axw.y * p0a.y + axw.z * p0b.x + axw.w * p0b.y;
            float ra1 = axw.x * p1a.x + axw.y * p1a.y + axw.z * p1b.x + axw.w * p1b.y;
            float ra2 = axw.x * p2a.x + axw.y * p2a.y + axw.z * p2b.x + axw.w * p2b.y;
            float rb0 = bxw.x * p0a.x + bxw.y * p0a.y + bxw.z * p0b.x + bxw.w * p0b.y;
            float rb1 = bxw.x * p1a.x + bxw.y * p1a.y + bxw.z * p1b.x + bxw.w * p1b.y;
            float rb2 = bxw.x * p2a.x + bxw.y * p2a.y + bxw.z * p2b.x + bxw.w * p2b.y;
            float sa = ayw.x * ra0 + ayw.y * ra1 + ayw.z * ra2;
            float sb = byw.x * rb0 + byw.y * rb1 + byw.z * rb2;
            acc += f * sb - 4.f * fprev[i] * sa;
            fprev[i] = f;
        }
    }

    red[q][lane] = acc;
    __syncthreads();
    if (tid < 64) {
        float s = red[0][tid] + red[1][tid] + red[2][tid] + red[3][tid];
        y[((size_t)n << 12) + o0 + tid] = s + bias[o0 + tid];
    }
}

// ---- fallback (r5 path, proven): fused per-(n,c) kernel with atomics ------
__global__ __launch_bounds__(256, 3) void fused_fallback_kernel(
    const float* __restrict__ x, const float* __restrict__ wrec,
    const float* __restrict__ feat, float* __restrict__ y)
{
    __shared__ __align__(16) float s_lo[SLOT];
    const int tid = threadIdx.x;
    const int n   = blockIdx.x >> 5;
    const int c   = blockIdx.x & 31;
    const float* img = x + ((size_t)(n * 32 + c) << 14);
    build_pyramid(img, s_lo, tid);

    const float4* W = (const float4*)wrec;
    float* yrow = y + ((size_t)n << 12);
    for (int out = tid; out < 4096; out += 256) {
        float4 w0 = W[out];
        float4 t1 = W[4096 + out];
        int o00 = __float_as_int(t1.x), o01 = __float_as_int(t1.y);
        int o10 = __float_as_int(t1.z), o11 = __float_as_int(t1.w);

        float f_prev = feat[((size_t)c << 12) + out];
        float v0 = w0.x * img[o00] + w0.y * img[o01] + w0.z * img[o10] + w0.w * img[o11];
        float acc = f_prev * v0;

#pragma unroll
        for (int j = 1; j <= 4; ++j) {
            const int mb = (2 + 5 * (j - 1)) * 4096 + out;
            const float4 axw = W[mb];
            const float4 bxw = W[mb + 4096];
            const float4 ayw = W[mb + 2 * 4096];
            const float4 byw = W[mb + 3 * 4096];
            const float4 rrf = W[mb + 4 * 4096];
            int r0 = __float_as_int(rrf.x);
            int r1 = __float_as_int(rrf.y);
            int r2 = __float_as_int(rrf.z);
            float f_cur = feat[((size_t)(j * 32 + c) << 12) + out];
            float2 p0a = *(const float2*)&s_lo[r0];
            float2 p0b = *(const float2*)&s_lo[r0 + 2];
            float2 p1a = *(const float2*)&s_lo[r1];
            float2 p1b = *(const float2*)&s_lo[r1 + 2];
            float2 p2a = *(const float2*)&s_lo[r2];
            float2 p2b = *(const float2*)&s_lo[r2 + 2];
            float ra0 = axw.x * p0a.x + axw.y * p0a.y + axw.z * p0b.x + axw.w * p0b.y;
            float ra1 = axw.x * p1a.x + axw.y * p1a.y + axw.z * p1b.x + axw.w * p1b.y;
            float ra2 = axw.x * p2a.x + axw.y * p2a.y + axw.z * p2b.x + axw.w * p2b.y;
            float rb0 = bxw.x * p0a.x + bxw.y * p0a.y + bxw.z * p0b.x + bxw.w * p0b.y;
            float rb1 = bxw.x * p1a.x + bxw.y * p1a.y + bxw.z * p1b.x + bxw.w * p1b.y;
            float rb2 = bxw.x * p2a.x + bxw.y * p2a.y + bxw.z * p2b.x + bxw.w * p2b.y;
            float sa = ayw.x * ra0 + ayw.y * ra1 + ayw.z * ra2;
            float sb = byw.x * rb0 + byw.y * rb1 + byw.z * rb2;
            acc += f_cur * sb - 4.f * f_prev * sa;
            f_prev = f_cur;
        }
        atomicAdd(&yrow[out], acc);
    }
}

extern "C" void kernel_launch(void* const* d_in, const int* in_sizes, int n_in,
                              void* d_out, int out_size, void* d_ws, size_t ws_size,
                              hipStream_t stream) {
    (void)in_sizes; (void)n_in;
    const float* x    = (const float*)d_in[0];
    const float* grid = (const float*)d_in[1];
    const float* feat = (const float*)d_in[2];
    const float* bias = (const float*)d_in[3];
    float* y  = (float*)d_out;
    float* ws = (float*)d_ws;

    weights_kernel<<<16, 256, 0, stream>>>(grid, ws);
    if (ws_size >= WS_NEED) {
        float* pyr = ws + PYR_OFF_FLOATS;
        pyr_build_kernel<<<2048, 256, 0, stream>>>(x, pyr);
        sample_kernel<<<4096, 256, 0, stream>>>(x, ws, pyr, feat, bias, y);
    } else {
        init_out_kernel<<<out_size / 256, 256, 0, stream>>>(bias, y);
        fused_fallback_kernel<<<2048, 256, 0, stream>>>(x, ws, feat, y);
    }
}

// Round 8
// 384.314 us; speedup vs baseline: 1.1717x; 1.1717x over previous
//
#include <hip/hip_runtime.h>
#include <hip/hip_fp16.h>

// ---------------------------------------------------------------------------
// SpatialTransformerPyramid2d fused, round 8.
// N=64, c=32, H=W=128, outdims=4096, SCALE_N=4.
//
// Identity: sample(hi_{j-1}) = bilin(img_{j-1}) - 4*stencil_{j-1}(lo_j);
// level-j bilinear taps lie inside the 3-tap stencil frame -> one 3x4 LDS
// patch per level serves both terms.
//
// r7 post-mortem: pyramid build alone = 183 us at 637 GB/s HBM (10% of
// achievable) -> MLP-starved scalar loads.  W table stream = 85 us L2 floor.
// Round-8 fixes, applied to the proven fused r5 structure:
//  1. Phase-1 uses 20 aligned float4 loads per 4-point window (5 rows x 4):
//     16x bytes per outstanding op -> HBM-saturating MLP.  5x redundant
//     fetch absorbed by L1/L2 (64 KB image, L2-resident per block).
//  2. W table compressed to fp16 weights + u16 offsets, SoA (176 B/out):
//     halves the 2048-block L2 stream (85 -> 43 us floor).
//
// VGPR rule (measured r1-r6): __launch_bounds__(256,3) -> cap 84, no spill;
// requesting more waves forces 40 regs + GB-scale scratch spills.
// ---------------------------------------------------------------------------

#define P1 66
#define P2 34
#define P3 18
#define P4 10
#define OFF_LO1 0                      // 64*66 = 4224
#define OFF_LO2 4224                   // 32*34 = 1088
#define OFF_LO3 5312                   // 16*18 = 288
#define OFF_LO4 5600                   // 8*10  = 80
#define SLOT    5680                   // floats per pyramid (22720 B)

#define G_A 0.0613609f
#define G_B 0.2447700f
#define G_C 0.3877386f

// compressed W layout in ws (float* base):
//   L0 table : uint4[4096]                      (64 KB)   at float offset 0
//   T  table : uint2[20][4096]                  (640 KB)  at float offset 16384
#define T_FOFF 16384

static __device__ __forceinline__ float clampf(float v, float lo, float hi) {
    return fminf(fmaxf(v, lo), hi);
}
static __device__ __forceinline__ int imin(int a, int b) { return a < b ? a : b; }
static __device__ __forceinline__ int imax(int a, int b) { return a > b ? a : b; }

static __device__ __forceinline__ unsigned int pack_h2(float a, float b) {
    __half ha = __float2half_rn(a), hb = __float2half_rn(b);
    unsigned short ua = *(unsigned short*)&ha, ub = *(unsigned short*)&hb;
    return (unsigned int)ua | ((unsigned int)ub << 16);
}
static __device__ __forceinline__ unsigned int pack_u2(int a, int b) {
    return (unsigned int)(a & 0xffff) | ((unsigned int)b << 16);
}
static __device__ __forceinline__ float2 uph2(unsigned int u) {
    unsigned short lo = (unsigned short)(u & 0xffff), hi = (unsigned short)(u >> 16);
    __half hl = *(__half*)&lo, hh = *(__half*)&hi;
    return make_float2(__half2float(hl), __half2float(hh));
}

__global__ void init_out_kernel(const float* __restrict__ bias, float* __restrict__ y) {
    int i = blockIdx.x * blockDim.x + threadIdx.x;
    y[i] = bias[i & 4095];
}

// ---------------------------------------------------------------------------
// weights: compressed SoA table, shared by all 2048 (n,c) images.
// ---------------------------------------------------------------------------
__global__ void weights_kernel(const float* __restrict__ grid, float* __restrict__ ws) {
    int out = blockIdx.x * blockDim.x + threadIdx.x;
    if (out >= 4096) return;
    float xs = clampf(grid[2 * out + 0], -1.f, 1.f);
    float ys = clampf(grid[2 * out + 1], -1.f, 1.f);

    uint4* L0 = (uint4*)ws;
    uint2* T  = (uint2*)(ws + T_FOFF);

    // level 0
    float fx = (xs + 1.f) * 64.f - 0.5f;
    float fy = (ys + 1.f) * 64.f - 0.5f;
    float x0f = floorf(fx), y0f = floorf(fy);
    int x0 = (int)x0f, y0 = (int)y0f;
    float wx = fx - x0f, wy = fy - y0f;
    float ux0 = (x0 >= 0)      ? (1.f - wx) : 0.f;
    float ux1 = (x0 + 1 < 128) ? wx         : 0.f;
    float uy0 = (y0 >= 0)      ? (1.f - wy) : 0.f;
    float uy1 = (y0 + 1 < 128) ? wy         : 0.f;
    int cx0 = imax(x0, 0), cx1 = imin(x0 + 1, 127);
    int cy0 = imax(y0, 0), cy1 = imin(y0 + 1, 127);
    L0[out] = make_uint4(pack_h2(ux0 * uy0, ux1 * uy0),
                         pack_h2(ux0 * uy1, ux1 * uy1),
                         pack_u2(cy0 * 128 + cx0, cy0 * 128 + cx1),
                         pack_u2(cy1 * 128 + cx0, cy1 * 128 + cx1));

    int   x0p = x0, y0p = y0;
    float ux0p = ux0, ux1p = ux1, uy0p = uy0, uy1p = uy1;

    const int offs[4]    = {OFF_LO1, OFF_LO2, OFF_LO3, OFF_LO4};
    const int strides[4] = {P1, P2, P3, P4};

    for (int j = 1; j <= 4; ++j) {
        const int Wj = 128 >> j, Pj = strides[j - 1], off = offs[j - 1];

        int qx; float a0, a1, a2;
        if (x0p & 1) { qx = (x0p - 1) >> 1;
            a0 = G_B * ux0p + G_A * ux1p; a1 = G_B * ux0p + G_C * ux1p; a2 = G_A * ux1p; }
        else         { qx = (x0p >> 1) - 1;
            a0 = G_A * ux0p; a1 = G_C * ux0p + G_B * ux1p; a2 = G_A * ux0p + G_B * ux1p; }
        int qy; float e0, e1, e2;
        if (y0p & 1) { qy = (y0p - 1) >> 1;
            e0 = G_B * uy0p + G_A * uy1p; e1 = G_B * uy0p + G_C * uy1p; e2 = G_A * uy1p; }
        else         { qy = (y0p >> 1) - 1;
            e0 = G_A * uy0p; e1 = G_C * uy0p + G_B * uy1p; e2 = G_A * uy0p + G_B * uy1p; }

        float half = (float)(Wj >> 1);
        float fxj = (xs + 1.f) * half - 0.5f;
        float fyj = (ys + 1.f) * half - 0.5f;
        float x0jf = floorf(fxj), y0jf = floorf(fyj);
        int x0j = (int)x0jf, y0j = (int)y0jf;
        float wxj = fxj - x0jf, wyj = fyj - y0jf;
        float ux0j = (x0j >= 0)     ? (1.f - wxj) : 0.f;
        float ux1j = (x0j + 1 < Wj) ? wxj         : 0.f;
        float uy0j = (y0j >= 0)     ? (1.f - wyj) : 0.f;
        float uy1j = (y0j + 1 < Wj) ? wyj         : 0.f;

        int bxb = qx & ~1;
        bxb = imin(imax(bxb, 0), Wj - 4);

        float axv[4], bxv[4], ayv[3], byv[3];
        int rv[3];
#pragma unroll
        for (int t = 0; t < 4; ++t) {
            int col = bxb + t;
            int s = col - qx;
            float av = (s == 0) ? a0 : (s == 1) ? a1 : (s == 2) ? a2 : 0.f;
            if (s < 0 || s > 2) av = 0.f;
            int sb = col - x0j;
            float bv = (sb == 0) ? ux0j : (sb == 1) ? ux1j : 0.f;
            axv[t] = av;
            bxv[t] = bv;
        }
#pragma unroll
        for (int t = 0; t < 3; ++t) {
            int row = qy + t;
            bool v = (row >= 0) && (row < Wj);
            float av = (t == 0) ? e0 : (t == 1) ? e1 : e2;
            ayv[t] = v ? av : 0.f;
            int sb = row - y0j;
            byv[t] = (sb == 0) ? uy0j : (sb == 1) ? uy1j : 0.f;
            int rc = imin(imax(row, 0), Wj - 1);
            rv[t] = off + rc * Pj + bxb;
        }

        int tb = (j - 1) * 5 * 4096 + out;
        T[tb]            = make_uint2(pack_h2(axv[0], axv[1]), pack_h2(axv[2], axv[3]));
        T[tb + 4096]     = make_uint2(pack_h2(bxv[0], bxv[1]), pack_h2(bxv[2], bxv[3]));
        T[tb + 2 * 4096] = make_uint2(pack_h2(ayv[0], ayv[1]), pack_h2(ayv[2], 0.f));
        T[tb + 3 * 4096] = make_uint2(pack_h2(byv[0], byv[1]), pack_h2(byv[2], 0.f));
        T[tb + 4 * 4096] = make_uint2(pack_u2(rv[0], rv[1]), pack_u2(rv[2], 0));

        x0p = x0j; y0p = y0j;
        ux0p = ux0j; ux1p = ux1j; uy0p = uy0j; uy1p = uy1j;
    }
}

// smooth+downsample one point from LDS src (stride, logical S x S, zero pad)
static __device__ __forceinline__ float down_pt_lds(const float* s, int stride, int S,
                                                    int i, int j) {
    const float g1[5] = {G_A, G_B, G_C, G_B, G_A};
    int by = 2 * i - 2, bx = 2 * j - 2;
    float acc = 0.f;
    if (by >= 0 && by + 4 < S && bx >= 0 && bx + 4 < S) {
#pragma unroll
        for (int dy = 0; dy < 5; ++dy) {
            const float* r = s + (by + dy) * stride + bx;
            acc += g1[dy] * (G_A * (r[0] + r[4]) + G_B * (r[1] + r[3]) + G_C * r[2]);
        }
    } else {
#pragma unroll
        for (int dy = 0; dy < 5; ++dy) {
            int yy = by + dy;
            if ((unsigned)yy < (unsigned)S) {
#pragma unroll
                for (int dx = 0; dx < 5; ++dx) {
                    int xx = bx + dx;
                    if ((unsigned)xx < (unsigned)S)
                        acc += g1[dy] * g1[dx] * s[yy * stride + xx];
                }
            }
        }
    }
    return acc;
}

__global__ __launch_bounds__(256, 3) void pyr_sample_kernel(
    const float* __restrict__ x, const float* __restrict__ wrec,
    const float* __restrict__ feat, float* __restrict__ y)
{
    __shared__ __align__(16) float s_lo[SLOT];
    const int tid = threadIdx.x;
    const int n   = blockIdx.x >> 5;   // 64
    const int c   = blockIdx.x & 31;   // 32
    const float* img = x + ((size_t)(n * 32 + c) << 14);

    const float g1[5] = {G_A, G_B, G_C, G_B, G_A};

    // ---- phase 1: lo1 (64x64), 4-point windows via aligned float4 loads ---
    for (int r = tid; r < 1024; r += 256) {
        int i = r >> 4, j0 = (r & 15) << 2;
        int by = 2 * i - 2;
        float acc[4] = {0.f, 0.f, 0.f, 0.f};
        if (i >= 1 && i <= 62 && j0 >= 4 && j0 <= 56) {
            const int a = 2 * j0 - 4;     // 16B-aligned, covers cols a..a+15
#pragma unroll
            for (int dy = 0; dy < 5; ++dy) {
                const float* rp = img + (by + dy) * 128 + a;
                float4 q0 = *(const float4*)(rp);
                float4 q1 = *(const float4*)(rp + 4);
                float4 q2 = *(const float4*)(rp + 8);
                float4 q3 = *(const float4*)(rp + 12);
                // window col bx+t = rp[t+2]
                float s2 = q0.z, s3 = q0.w, s4 = q1.x, s5 = q1.y, s6 = q1.z,
                      s7 = q1.w, s8 = q2.x, s9 = q2.y, s10 = q2.z, s11 = q2.w,
                      s12 = q3.x;
                float g = g1[dy];
                acc[0] += g * (G_A * (s2 + s6)  + G_B * (s3 + s5)  + G_C * s4);
                acc[1] += g * (G_A * (s4 + s8)  + G_B * (s5 + s7)  + G_C * s6);
                acc[2] += g * (G_A * (s6 + s10) + G_B * (s7 + s9)  + G_C * s8);
                acc[3] += g * (G_A * (s8 + s12) + G_B * (s9 + s11) + G_C * s10);
            }
        } else {
            int bx = 2 * j0 - 2;
#pragma unroll
            for (int dy = 0; dy < 5; ++dy) {
                int yy = by + dy;
                if ((unsigned)yy < 128u) {
#pragma unroll
                    for (int t = 0; t < 11; ++t) {
                        int xx = bx + t;
                        if ((unsigned)xx < 128u) {
                            float v = img[yy * 128 + xx];
#pragma unroll
                            for (int jj = 0; jj < 4; ++jj) {
                                int dx = t - 2 * jj;
                                if (dx >= 0 && dx <= 4) acc[jj] += g1[dy] * g1[dx] * v;
                            }
                        }
                    }
                }
            }
        }
        int base = OFF_LO1 + i * P1 + j0;   // even (P1 even, j0%4==0)
        *(float2*)&s_lo[base]     = make_float2(acc[0], acc[1]);
        *(float2*)&s_lo[base + 2] = make_float2(acc[2], acc[3]);
    }
    __syncthreads();

    // ---- phase 2: lo2 (32x32) ----
    for (int p = tid; p < 1024; p += 256) {
        int i = p >> 5, j = p & 31;
        s_lo[OFF_LO2 + i * P2 + j] = down_pt_lds(s_lo + OFF_LO1, P1, 64, i, j);
    }
    __syncthreads();

    // ---- phase 3: lo3 (16x16) ----
    {
        int i = tid >> 4, j = tid & 15;
        s_lo[OFF_LO3 + i * P3 + j] = down_pt_lds(s_lo + OFF_LO2, P2, 32, i, j);
    }
    __syncthreads();

    // ---- phase 4: lo4 (8x8) ----
    if (tid < 64) {
        int i = tid >> 3, j = tid & 7;
        s_lo[OFF_LO4 + i * P4 + j] = down_pt_lds(s_lo + OFF_LO3, P3, 16, i, j);
    }
    __syncthreads();

    // ---- phase 5: sample + contract, compressed SoA weights ---------------
    const uint4* L0 = (const uint4*)wrec;
    const uint2* T  = (const uint2*)(wrec + T_FOFF);
    float* yrow = y + ((size_t)n << 12);
    for (int out = tid; out < 4096; out += 256) {
        uint4 h0 = L0[out];
        float2 wA = uph2(h0.x), wB = uph2(h0.y);
        int o00 = (int)(h0.z & 0xffff), o01 = (int)(h0.z >> 16);
        int o10 = (int)(h0.w & 0xffff), o11 = (int)(h0.w >> 16);

        float f_prev = feat[((size_t)c << 12) + out];
        float v0 = wA.x * img[o00] + wA.y * img[o01] + wB.x * img[o10] + wB.y * img[o11];
        float acc = f_prev * v0;

#pragma unroll
        for (int j = 1; j <= 4; ++j) {
            const int tb = (j - 1) * 5 * 4096 + out;
            uint2 uAX = T[tb];
            uint2 uBX = T[tb + 4096];
            uint2 uAY = T[tb + 2 * 4096];
            uint2 uBY = T[tb + 3 * 4096];
            uint2 uR  = T[tb + 4 * 4096];
            float2 ax01 = uph2(uAX.x), ax23 = uph2(uAX.y);
            float2 bx01 = uph2(uBX.x), bx23 = uph2(uBX.y);
            float2 ay01 = uph2(uAY.x); float ay2 = uph2(uAY.y).x;
            float2 by01 = uph2(uBY.x); float by2 = uph2(uBY.y).x;
            int r0 = (int)(uR.x & 0xffff), r1 = (int)(uR.x >> 16), r2 = (int)(uR.y & 0xffff);

            float f_cur = feat[((size_t)(j * 32 + c) << 12) + out];

            float2 p0a = *(const float2*)&s_lo[r0];
            float2 p0b = *(const float2*)&s_lo[r0 + 2];
            float2 p1a = *(const float2*)&s_lo[r1];
            float2 p1b = *(const float2*)&s_lo[r1 + 2];
            float2 p2a = *(const float2*)&s_lo[r2];
            float2 p2b = *(const float2*)&s_lo[r2 + 2];
            float ra0 = ax01.x * p0a.x + ax01.y * p0a.y + ax23.x * p0b.x + ax23.y * p0b.y;
            float ra1 = ax01.x * p1a.x + ax01.y * p1a.y + ax23.x * p1b.x + ax23.y * p1b.y;
            float ra2 = ax01.x * p2a.x + ax01.y * p2a.y + ax23.x * p2b.x + ax23.y * p2b.y;
            float rb0 = bx01.x * p0a.x + bx01.y * p0a.y + bx23.x * p0b.x + bx23.y * p0b.y;
            float rb1 = bx01.x * p1a.x + bx01.y * p1a.y + bx23.x * p1b.x + bx23.y * p1b.y;
            float rb2 = bx01.x * p2a.x + bx01.y * p2a.y + bx23.x * p2b.x + bx23.y * p2b.y;
            float sa = ay01.x * ra0 + ay01.y * ra1 + ay2 * ra2;
            float sb = by01.x * rb0 + by01.y * rb1 + by2 * rb2;
            acc += f_cur * sb - 4.f * f_prev * sa;
            f_prev = f_cur;
        }
        atomicAdd(&yrow[out], acc);
    }
}

extern "C" void kernel_launch(void* const* d_in, const int* in_sizes, int n_in,
                              void* d_out, int out_size, void* d_ws, size_t ws_size,
                              hipStream_t stream) {
    (void)in_sizes; (void)n_in; (void)ws_size;
    const float* x    = (const float*)d_in[0];
    const float* grid = (const float*)d_in[1];
    const float* feat = (const float*)d_in[2];
    const float* bias = (const float*)d_in[3];
    float* y  = (float*)d_out;
    float* ws = (float*)d_ws;

    weights_kernel<<<16, 256, 0, stream>>>(grid, ws);
    init_out_kernel<<<out_size / 256, 256, 0, stream>>>(bias, y);
    pyr_sample_kernel<<<2048, 256, 0, stream>>>(x, ws, feat, y);
}